// Round 4
// baseline (587.011 us; speedup 1.0000x reference)
//
#include <hip/hip_runtime.h>

// ============================================================================
// PlasticityModelMoE — MI355X (gfx950).
//
// Dtype model (round-4): inputs f32 (round-1 bf16-read gave NaN => inputs are
// f32), OUTPUT f32 (round-2/3 bf16 writes gave the exact "scrambled colmean +
// zero tail" error signature of an f32-read buffer; "(bf16" in the test label
// is hard-coded generator text). Internals: bf16 MFMA GEMMs, f32 accum.
//
// Math refactor: z[n,u] = sum_k y[n,k]*W[u,k], k=d*4+b, y[n,k]=x[n,d]*gate[n,b],
// W[u,k]=w[d,u,b]*sigmoid(delay[d,u,b])  (gate contraction folded into K=4096).
//
// Pipeline: k_small (conn,wts) -> k_gate_y -> k_wmT -> GEMM-A(+fused epilogue:
// dendritic bias, conn*mask, relu, 8-way activation blend) -> transpose(read_W)
// -> GEMM-B(+read_b) -> in-place row softmax -> transpose(memory, aliased onto
// dead y buffer) -> GEMM-C -> d_out (f32).
// ============================================================================

typedef unsigned short u16;
typedef __attribute__((ext_vector_type(8))) short bf16x8;   // 8 bf16 = 4 VGPRs
typedef __attribute__((ext_vector_type(4))) float f32x4;

__device__ __forceinline__ float b2f(u16 h) {
    union { unsigned u; float f; } v; v.u = ((unsigned)h) << 16; return v.f;
}
__device__ __forceinline__ u16 f2b(float f) {
    union { float f; unsigned u; } v; v.f = f;
    unsigned u = v.u;
    return (u16)((u + 0x7fffu + ((u >> 16) & 1u)) >> 16);   // round-nearest-even
}

// async global->LDS, 16B per lane (wave-uniform base + lane*16 — m97 pattern).
// Proven bit-identical to VGPR staging on this pipeline (rounds 2/3).
__device__ __forceinline__ void async_copy16(void* lds, const void* g) {
    __builtin_amdgcn_global_load_lds(
        (__attribute__((address_space(1))) void*)(g),
        (__attribute__((address_space(3))) void*)(lds), 16, 0, 0);
}

// ---------------------------------------------------------------------------
// GEMM core: C[M,N] += A[M,K] * B[N,K]^T, bf16 in, f32 acc. BK=32, 256 thr,
// 4 waves 2x2, wave tile (BM/2)x(BN/2), mfma_f32_16x16x32_bf16.
// Layouts (m89/m91): A-frag A[m=lane&15][k=(lane>>4)*8+j]; B-frag
// B^T[n=lane&15][k=(lane>>4)*8+j]; C/D col(n)=lane&15, row(m)=(lane>>4)*4+reg.
// ---------------------------------------------------------------------------
template<int BM, int BN>
__device__ __forceinline__ void gemm_core(const u16* __restrict__ A,
                                          const u16* __restrict__ B,
                                          int K, int row0, int col0,
                                          u16* sA, u16* sB,
                                          f32x4 (&acc)[BM / 32][BN / 32])
{
    constexpr int MT = BM / 32, NT = BN / 32;
    const int tid  = threadIdx.x;
    const int lane = tid & 63;
    const int wv   = tid >> 6;
    const int wr   = wv >> 1, wc = wv & 1;
    const int lr   = lane & 15, kg = lane >> 4;

#pragma unroll
    for (int i = 0; i < MT; i++)
#pragma unroll
        for (int j = 0; j < NT; j++) {
            f32x4 z = {0.f, 0.f, 0.f, 0.f};
            acc[i][j] = z;
        }

    for (int k0 = 0; k0 < K; k0 += 32) {
        __syncthreads();
#pragma unroll
        for (int c = tid; c < BM * 4; c += 256)
            async_copy16(sA + c * 8,
                         A + (size_t)(row0 + (c >> 2)) * K + k0 + (c & 3) * 8);
#pragma unroll
        for (int c = tid; c < BN * 4; c += 256)
            async_copy16(sB + c * 8,
                         B + (size_t)(col0 + (c >> 2)) * K + k0 + (c & 3) * 8);
        __syncthreads();   // drains vmcnt (global_load_lds)

        bf16x8 af[MT], bfr[NT];
#pragma unroll
        for (int i = 0; i < MT; i++)
            af[i] = *(const bf16x8*)(sA + ((wr * (BM / 2) + i * 16 + lr) * 32 + kg * 8));
#pragma unroll
        for (int j = 0; j < NT; j++)
            bfr[j] = *(const bf16x8*)(sB + ((wc * (BN / 2) + j * 16 + lr) * 32 + kg * 8));
#pragma unroll
        for (int i = 0; i < MT; i++)
#pragma unroll
            for (int j = 0; j < NT; j++)
                acc[i][j] = __builtin_amdgcn_mfma_f32_16x16x32_bf16(
                                af[i], bfr[j], acc[i][j], 0, 0, 0);
    }
}

// ---------------------------------------------------------------------------
// tiny: conn = sigmoid(relu(na@W1+b1)@W2+b2), wts = softmax(act_w). All f32.
// ---------------------------------------------------------------------------
__global__ __launch_bounds__(256)
void k_small(const float* __restrict__ na, const float* __restrict__ W1,
             const float* __restrict__ b1, const float* __restrict__ W2,
             const float* __restrict__ b2, const float* __restrict__ actw,
             float* __restrict__ conn, float* __restrict__ wts)
{
    __shared__ float red[256 * 32];
    __shared__ float hsh[32];
    const int tid = threadIdx.x;
    float h[32];
#pragma unroll
    for (int k = 0; k < 32; k++) h[k] = 0.f;
    for (int u = tid; u < 2048; u += 256) {
        float nav = na[u];
        const float* row = W1 + u * 32;
#pragma unroll
        for (int k = 0; k < 32; k++) h[k] += nav * row[k];
    }
#pragma unroll
    for (int k = 0; k < 32; k++) red[tid * 32 + k] = h[k];
    for (int s = 128; s > 0; s >>= 1) {
        __syncthreads();
        if (tid < s)
#pragma unroll
            for (int k = 0; k < 32; k++) red[tid * 32 + k] += red[(tid + s) * 32 + k];
    }
    __syncthreads();
    if (tid < 32) hsh[tid] = fmaxf(red[tid] + b1[tid], 0.f);
    if (tid == 0) {
        float e[9], m = -1e30f;
        for (int i = 0; i < 9; i++) { e[i] = actw[i]; m = fmaxf(m, e[i]); }
        float s = 0.f;
        for (int i = 0; i < 9; i++) { e[i] = expf(e[i] - m); s += e[i]; }
        for (int i = 0; i < 9; i++) wts[i] = e[i] / s;
    }
    __syncthreads();
    for (int u = tid; u < 2048; u += 256) {
        float a = 0.f;
#pragma unroll
        for (int k = 0; k < 32; k++) a += hsh[k] * W2[k * 2048 + u];
        conn[u] = 1.f / (1.f + expf(-(a + b2[u])));
    }
}

// ---------------------------------------------------------------------------
// gate softmax + y = x*gate (bf16 out). One wave per row n.
// y[n, d*4+p] = x[n,d]*gate[n,p]
// ---------------------------------------------------------------------------
__global__ __launch_bounds__(256)
void k_gate_y(const float* __restrict__ x, const float* __restrict__ gW,
              const float* __restrict__ gb, float* __restrict__ gate,
              u16* __restrict__ y)
{
    const int tid = threadIdx.x, lane = tid & 63, wv = tid >> 6;
    const int n = blockIdx.x * 4 + wv;
    const float* xr = x + (size_t)n * 1024;
    float a0 = 0, a1 = 0, a2 = 0, a3 = 0;
    float xv[16];
#pragma unroll
    for (int s = 0; s < 16; s++) {
        int d = s * 64 + lane;
        float xd = xr[d]; xv[s] = xd;
        float4 g4 = *(const float4*)(gW + d * 4);
        a0 += xd * g4.x; a1 += xd * g4.y; a2 += xd * g4.z; a3 += xd * g4.w;
    }
#pragma unroll
    for (int off = 32; off > 0; off >>= 1) {
        a0 += __shfl_xor(a0, off); a1 += __shfl_xor(a1, off);
        a2 += __shfl_xor(a2, off); a3 += __shfl_xor(a3, off);
    }
    a0 += gb[0]; a1 += gb[1]; a2 += gb[2]; a3 += gb[3];
    float m = fmaxf(fmaxf(a0, a1), fmaxf(a2, a3));
    float e0 = expf(a0 - m), e1 = expf(a1 - m), e2 = expf(a2 - m), e3 = expf(a3 - m);
    float inv = 1.f / (e0 + e1 + e2 + e3);
    float g0 = e0 * inv, g1 = e1 * inv, g2 = e2 * inv, g3 = e3 * inv;
    if (lane == 0) *(float4*)(gate + n * 4) = make_float4(g0, g1, g2, g3);
#pragma unroll
    for (int s = 0; s < 16; s++) {
        int d = s * 64 + lane;
        ushort4 o;
        o.x = f2b(xv[s] * g0); o.y = f2b(xv[s] * g1);
        o.z = f2b(xv[s] * g2); o.w = f2b(xv[s] * g3);
        *(ushort4*)(y + (size_t)n * 4096 + d * 4) = o;
    }
}

// ---------------------------------------------------------------------------
// wmT[u, d*4+b] = w[d,u,b] * sigmoid(delay[d,u,b]); f32 in, bf16 out.
// ---------------------------------------------------------------------------
__global__ __launch_bounds__(256)
void k_wmT(const float* __restrict__ w, const float* __restrict__ delay,
           u16* __restrict__ wmT)
{
    __shared__ __align__(16) ushort4 tile[32][65];
    const int tid = threadIdx.x;
    const int tx = tid & 63, ty = tid >> 6;          // tx: u, ty: d-subset
    const int u0 = blockIdx.x * 64, d0 = blockIdx.y * 32;
#pragma unroll
    for (int i = 0; i < 8; i++) {
        int d = i * 4 + ty;
        size_t idx = ((size_t)(d0 + d) * 2048 + (u0 + tx)) * 4;
        float4 w4 = *(const float4*)(w + idx);
        float4 d4 = *(const float4*)(delay + idx);
        ushort4 o;
        o.x = f2b(w4.x / (1.f + expf(-d4.x)));
        o.y = f2b(w4.y / (1.f + expf(-d4.y)));
        o.z = f2b(w4.z / (1.f + expf(-d4.z)));
        o.w = f2b(w4.w / (1.f + expf(-d4.w)));
        tile[d][tx] = o;
    }
    __syncthreads();
    const int dx = tid & 31, uy = tid >> 5;
#pragma unroll
    for (int i = 0; i < 8; i++) {
        int u = i * 8 + uy;
        *(ushort4*)(wmT + (size_t)(u0 + u) * 4096 + (d0 + dx) * 4) = tile[dx][u];
    }
}

// ---------------------------------------------------------------------------
// transpose + cast: in[R,C] f32 -> out[C,R] bf16, 64x64 tiles
// ---------------------------------------------------------------------------
__global__ __launch_bounds__(256)
void k_transpose(const float* __restrict__ in, u16* __restrict__ out, int R, int C)
{
    __shared__ __align__(16) u16 t[64][68];
    const int tid = threadIdx.x, tx = tid & 15, ty = tid >> 4;
    const int c0 = blockIdx.x * 64, r0 = blockIdx.y * 64;
#pragma unroll
    for (int i = 0; i < 4; i++) {
        int r = r0 + ty + i * 16;
        float4 v = *(const float4*)(in + (size_t)r * C + c0 + tx * 4);
        t[tx * 4 + 0][ty + i * 16] = f2b(v.x); t[tx * 4 + 1][ty + i * 16] = f2b(v.y);
        t[tx * 4 + 2][ty + i * 16] = f2b(v.z); t[tx * 4 + 3][ty + i * 16] = f2b(v.w);
    }
    __syncthreads();
#pragma unroll
    for (int i = 0; i < 4; i++) {
        int c = ty + i * 16;
        ushort4 v;
        v.x = t[c][tx * 4 + 0]; v.y = t[c][tx * 4 + 1];
        v.z = t[c][tx * 4 + 2]; v.w = t[c][tx * 4 + 3];
        *(ushort4*)(out + (size_t)(c0 + c) * R + r0 + tx * 4) = v;
    }
}

// ---------------------------------------------------------------------------
// 8-way activation blend
// ---------------------------------------------------------------------------
__device__ __forceinline__ float act_blend(float a,
    float w0, float w1, float w2, float w3,
    float w4, float w5, float w6, float w7)
{
    float sig = 1.f / (1.f + expf(-a));
    float elu = (a > 0.f) ? a : (expf(a) - 1.f);
    float th  = tanhf(a);
    float rel = fmaxf(a, 0.f);
    float sil = a * sig;
    float gel = a * 0.5f * (1.f + erff(a * 0.70710678118654752f));
    float sel = (a > 0.f) ? 1.0507009873554805f * a
                          : 1.0507009873554805f * 1.6732632423543772f * (expf(a) - 1.f);
    float sp  = (a > 20.f) ? a : log1pf(expf(a));
    float mish = a * tanhf(sp);
    return w0 * sig + w1 * elu + w2 * th + w3 * rel + w4 * sil + w5 * gel
         + w6 * sel + w7 * mish;
}

// ---------------------------------------------------------------------------
// GEMM-A: blend[n,u] = blend8(relu((y@wmT^T + b·gate)[n,u]*conn[u]*mask[u]))
// ---------------------------------------------------------------------------
__global__ __launch_bounds__(256, 2)
void k_gemm_blend(const u16* __restrict__ Y, const u16* __restrict__ WMT,
                  const float* __restrict__ gate, const float* __restrict__ conn,
                  const float* __restrict__ wts,
                  const float* __restrict__ bbias, const float* __restrict__ mask,
                  u16* __restrict__ blend)
{
    __shared__ __align__(16) u16 smem[(128 + 128) * 32];
    f32x4 acc[4][4];
    const int row0 = blockIdx.y * 128, col0 = blockIdx.x * 128;
    gemm_core<128, 128>(Y, WMT, 4096, row0, col0, smem, smem + 128 * 32, acc);

    const int tid = threadIdx.x, lane = tid & 63, wv = tid >> 6;
    const int wr = wv >> 1, wc = wv & 1, lr = lane & 15, kg = lane >> 4;
    const float w0 = wts[0], w1 = wts[1], w2 = wts[2], w3 = wts[3];
    const float w4 = wts[4], w5 = wts[5], w6 = wts[6], w7 = wts[7];

    float cm[4], bb0[4], bb1[4], bb2[4], bb3[4];
    int uu[4];
#pragma unroll
    for (int j = 0; j < 4; j++) {
        int u = col0 + wc * 64 + j * 16 + lr;
        uu[j] = u;
        cm[j] = conn[u] * mask[u];
        float4 b4 = *(const float4*)(bbias + u * 4);
        bb0[j] = b4.x; bb1[j] = b4.y; bb2[j] = b4.z; bb3[j] = b4.w;
    }
#pragma unroll
    for (int i = 0; i < 4; i++) {
#pragma unroll
        for (int r = 0; r < 4; r++) {
            int n = row0 + wr * 64 + i * 16 + kg * 4 + r;
            float4 g = *(const float4*)(gate + n * 4);
            size_t ob = (size_t)n * 2048;
#pragma unroll
            for (int j = 0; j < 4; j++) {
                float z = acc[i][j][r] + g.x * bb0[j] + g.y * bb1[j]
                                       + g.z * bb2[j] + g.w * bb3[j];
                float a = fmaxf(z * cm[j], 0.f);
                blend[ob + uu[j]] = f2b(act_blend(a, w0, w1, w2, w3, w4, w5, w6, w7));
            }
        }
    }
}

// ---------------------------------------------------------------------------
// GEMM-B: logits[n,m] = blend@read_W + read_b (bf16 out; softmaxed in place)
// ---------------------------------------------------------------------------
__global__ __launch_bounds__(256, 2)
void k_gemm_logits(const u16* __restrict__ BL, const u16* __restrict__ RWT,
                   const float* __restrict__ rbias, u16* __restrict__ out)
{
    __shared__ __align__(16) u16 smem[(128 + 128) * 32];
    f32x4 acc[4][4];
    const int row0 = blockIdx.y * 128, col0 = blockIdx.x * 128;
    gemm_core<128, 128>(BL, RWT, 2048, row0, col0, smem, smem + 128 * 32, acc);

    const int tid = threadIdx.x, lane = tid & 63, wv = tid >> 6;
    const int wr = wv >> 1, wc = wv & 1, lr = lane & 15, kg = lane >> 4;
    float rb[4]; int mm[4];
#pragma unroll
    for (int j = 0; j < 4; j++) {
        mm[j] = col0 + wc * 64 + j * 16 + lr;
        rb[j] = rbias[mm[j]];
    }
#pragma unroll
    for (int i = 0; i < 4; i++)
#pragma unroll
        for (int r = 0; r < 4; r++) {
            int n = row0 + wr * 64 + i * 16 + kg * 4 + r;
            size_t ob = (size_t)n * 8192;
#pragma unroll
            for (int j = 0; j < 4; j++)
                out[ob + mm[j]] = f2b(acc[i][j][r] + rb[j]);
        }
}

// ---------------------------------------------------------------------------
// in-place row softmax over 8192 bf16 (one block per row, values in registers)
// ---------------------------------------------------------------------------
__global__ __launch_bounds__(256)
void k_softmax(u16* __restrict__ buf)
{
    __shared__ float red[8];
    const int tid = threadIdx.x, lane = tid & 63, wv = tid >> 6;
    u16* row = buf + (size_t)blockIdx.x * 8192;
    float v[32];
    float mx = -1e30f;
#pragma unroll
    for (int s = 0; s < 8; s++) {
        ushort4 u4 = *(const ushort4*)(row + (s * 256 + tid) * 4);
        float a = b2f(u4.x), b = b2f(u4.y), c = b2f(u4.z), d = b2f(u4.w);
        v[s * 4 + 0] = a; v[s * 4 + 1] = b; v[s * 4 + 2] = c; v[s * 4 + 3] = d;
        mx = fmaxf(mx, fmaxf(fmaxf(a, b), fmaxf(c, d)));
    }
#pragma unroll
    for (int off = 32; off > 0; off >>= 1) mx = fmaxf(mx, __shfl_xor(mx, off));
    if (lane == 0) red[wv] = mx;
    __syncthreads();
    mx = fmaxf(fmaxf(red[0], red[1]), fmaxf(red[2], red[3]));
    float sum = 0.f;
#pragma unroll
    for (int k = 0; k < 32; k++) { v[k] = expf(v[k] - mx); sum += v[k]; }
#pragma unroll
    for (int off = 32; off > 0; off >>= 1) sum += __shfl_xor(sum, off);
    if (lane == 0) red[4 + wv] = sum;
    __syncthreads();
    float inv = 1.f / (red[4] + red[5] + red[6] + red[7]);
#pragma unroll
    for (int s = 0; s < 8; s++) {
        ushort4 o;
        o.x = f2b(v[s * 4 + 0] * inv); o.y = f2b(v[s * 4 + 1] * inv);
        o.z = f2b(v[s * 4 + 2] * inv); o.w = f2b(v[s * 4 + 3] * inv);
        *(ushort4*)(row + (s * 256 + tid) * 4) = o;
    }
}

// ---------------------------------------------------------------------------
// GEMM-C: out[n,md] = attn @ memory (BM=64 -> 256 blocks; K=8192), f32 out
// ---------------------------------------------------------------------------
__global__ __launch_bounds__(256, 2)
void k_gemm_out(const u16* __restrict__ AT, const u16* __restrict__ MEMT,
                float* __restrict__ out)
{
    __shared__ __align__(16) u16 smem[(64 + 128) * 32];
    f32x4 acc[2][4];
    const int row0 = blockIdx.y * 64, col0 = blockIdx.x * 128;
    gemm_core<64, 128>(AT, MEMT, 8192, row0, col0, smem, smem + 64 * 32, acc);

    const int tid = threadIdx.x, lane = tid & 63, wv = tid >> 6;
    const int wr = wv >> 1, wc = wv & 1, lr = lane & 15, kg = lane >> 4;
    int mm[4];
#pragma unroll
    for (int j = 0; j < 4; j++) mm[j] = col0 + wc * 64 + j * 16 + lr;
#pragma unroll
    for (int i = 0; i < 2; i++)
#pragma unroll
        for (int r = 0; r < 4; r++) {
            int n = row0 + wr * 32 + i * 16 + kg * 4 + r;
            size_t ob = (size_t)n * 1024;
#pragma unroll
            for (int j = 0; j < 4; j++)
                out[ob + mm[j]] = acc[i][j][r];
        }
}

// sentinel: distinctive output if workspace is too small (absmax ~12345)
__global__ void k_fill(float* out, int n)
{
    int i = blockIdx.x * 256 + threadIdx.x;
    if (i < n) out[i] = 12345.f;
}

// ---------------------------------------------------------------------------
extern "C" void kernel_launch(void* const* d_in, const int* in_sizes, int n_in,
                              void* d_out, int out_size, void* d_ws, size_t ws_size,
                              hipStream_t stream)
{
    const float* x     = (const float*)d_in[0];
    const float* w     = (const float*)d_in[1];
    const float* delay = (const float*)d_in[2];
    const float* bb    = (const float*)d_in[3];
    const float* gW    = (const float*)d_in[4];
    const float* gb    = (const float*)d_in[5];
    const float* na    = (const float*)d_in[6];
    const float* cW1   = (const float*)d_in[7];
    const float* cb1   = (const float*)d_in[8];
    const float* cW2   = (const float*)d_in[9];
    const float* cb2   = (const float*)d_in[10];
    const float* mask  = (const float*)d_in[11];
    const float* actw  = (const float*)d_in[12];
    const float* rW    = (const float*)d_in[13];
    const float* rb    = (const float*)d_in[14];
    const float* mem   = (const float*)d_in[15];
    (void)in_sizes; (void)n_in;

    char* ws = (char*)d_ws;
    size_t off = 0;
    auto alloc = [&](size_t bytes) {
        size_t o = off; off += (bytes + 255) & ~(size_t)255; return o;
    };
    size_t o_wts   = alloc(9 * 4);
    size_t o_gate  = alloc(2048 * 4 * 4);
    size_t o_conn  = alloc(2048 * 4);
    size_t o_y     = alloc((size_t)2048 * 4096 * 2);   // later aliased as memT
    size_t o_wmT   = alloc((size_t)2048 * 4096 * 2);
    size_t o_blend = alloc((size_t)2048 * 2048 * 2);
    size_t o_rwT   = alloc((size_t)8192 * 2048 * 2);
    size_t o_log   = alloc((size_t)2048 * 8192 * 2);   // logits, then attn in-place

    if (off > ws_size) {   // loud, distinguishable failure mode
        k_fill<<<(out_size + 255) / 256, 256, 0, stream>>>((float*)d_out, out_size);
        return;
    }

    float* wts   = (float*)(ws + o_wts);
    float* gate  = (float*)(ws + o_gate);
    float* conn  = (float*)(ws + o_conn);
    u16* y       = (u16*)(ws + o_y);
    u16* wmT     = (u16*)(ws + o_wmT);
    u16* blend   = (u16*)(ws + o_blend);
    u16* rwT     = (u16*)(ws + o_rwT);
    u16* logits  = (u16*)(ws + o_log);
    u16* memT    = y;   // y dead after k_gemm_blend; same size (16 MB)

    k_small<<<1, 256, 0, stream>>>(na, cW1, cb1, cW2, cb2, actw, conn, wts);
    k_gate_y<<<512, 256, 0, stream>>>(x, gW, gb, gate, y);
    k_wmT<<<dim3(32, 32), 256, 0, stream>>>(w, delay, wmT);
    k_gemm_blend<<<dim3(16, 16), 256, 0, stream>>>(y, wmT, gate, conn, wts, bb, mask, blend);
    k_transpose<<<dim3(128, 32), 256, 0, stream>>>(rW, rwT, 2048, 8192);
    k_gemm_logits<<<dim3(64, 16), 256, 0, stream>>>(blend, rwT, rb, logits);
    k_softmax<<<2048, 256, 0, stream>>>(logits);
    k_transpose<<<dim3(16, 128), 256, 0, stream>>>(mem, memT, 8192, 1024);
    k_gemm_out<<<dim3(8, 32), 256, 0, stream>>>(logits, memT, (float*)d_out);
}

// Round 5
// 531.428 us; speedup vs baseline: 1.1046x; 1.1046x over previous
//
#include <hip/hip_runtime.h>

// ============================================================================
// PlasticityModelMoE — MI355X (gfx950). PASSING config (round 4): inputs f32,
// output f32, bf16 MFMA internals. This round: occupancy fix for GEMM-A/C —
// 1 block/CU (256-block grids) was the bottleneck (Occupancy 11%, MfmaUtil 9%).
// A: 128x64 tiles (512 blocks, 2/CU). C: 64x64 tiles (512 blocks, 2/CU).
// B stays 128x128 (1024 blocks, 4/CU — m97 sweet spot).
// ============================================================================

typedef unsigned short u16;
typedef __attribute__((ext_vector_type(8))) short bf16x8;   // 8 bf16 = 4 VGPRs
typedef __attribute__((ext_vector_type(4))) float f32x4;

__device__ __forceinline__ float b2f(u16 h) {
    union { unsigned u; float f; } v; v.u = ((unsigned)h) << 16; return v.f;
}
__device__ __forceinline__ u16 f2b(float f) {
    union { float f; unsigned u; } v; v.f = f;
    unsigned u = v.u;
    return (u16)((u + 0x7fffu + ((u >> 16) & 1u)) >> 16);   // round-nearest-even
}

// async global->LDS, 16B per lane (wave-uniform base + lane*16 — m97 pattern).
__device__ __forceinline__ void async_copy16(void* lds, const void* g) {
    __builtin_amdgcn_global_load_lds(
        (__attribute__((address_space(1))) void*)(g),
        (__attribute__((address_space(3))) void*)(lds), 16, 0, 0);
}

// ---------------------------------------------------------------------------
// GEMM core: C[M,N] += A[M,K] * B[N,K]^T, bf16 in, f32 acc. BK=32, 256 thr,
// 4 waves 2x2, wave tile (BM/2)x(BN/2), mfma_f32_16x16x32_bf16.
// Layouts (m89/m91): A-frag A[m=lane&15][k=(lane>>4)*8+j]; B-frag
// B^T[n=lane&15][k=(lane>>4)*8+j]; C/D col(n)=lane&15, row(m)=(lane>>4)*4+reg.
// ---------------------------------------------------------------------------
template<int BM, int BN>
__device__ __forceinline__ void gemm_core(const u16* __restrict__ A,
                                          const u16* __restrict__ B,
                                          int K, int row0, int col0,
                                          u16* sA, u16* sB,
                                          f32x4 (&acc)[BM / 32][BN / 32])
{
    constexpr int MT = BM / 32, NT = BN / 32;
    const int tid  = threadIdx.x;
    const int lane = tid & 63;
    const int wv   = tid >> 6;
    const int wr   = wv >> 1, wc = wv & 1;
    const int lr   = lane & 15, kg = lane >> 4;

#pragma unroll
    for (int i = 0; i < MT; i++)
#pragma unroll
        for (int j = 0; j < NT; j++) {
            f32x4 z = {0.f, 0.f, 0.f, 0.f};
            acc[i][j] = z;
        }

    for (int k0 = 0; k0 < K; k0 += 32) {
        __syncthreads();
#pragma unroll
        for (int c = tid; c < BM * 4; c += 256)
            async_copy16(sA + c * 8,
                         A + (size_t)(row0 + (c >> 2)) * K + k0 + (c & 3) * 8);
#pragma unroll
        for (int c = tid; c < BN * 4; c += 256)
            async_copy16(sB + c * 8,
                         B + (size_t)(col0 + (c >> 2)) * K + k0 + (c & 3) * 8);
        __syncthreads();   // drains vmcnt (global_load_lds)

        bf16x8 af[MT], bfr[NT];
#pragma unroll
        for (int i = 0; i < MT; i++)
            af[i] = *(const bf16x8*)(sA + ((wr * (BM / 2) + i * 16 + lr) * 32 + kg * 8));
#pragma unroll
        for (int j = 0; j < NT; j++)
            bfr[j] = *(const bf16x8*)(sB + ((wc * (BN / 2) + j * 16 + lr) * 32 + kg * 8));
#pragma unroll
        for (int i = 0; i < MT; i++)
#pragma unroll
            for (int j = 0; j < NT; j++)
                acc[i][j] = __builtin_amdgcn_mfma_f32_16x16x32_bf16(
                                af[i], bfr[j], acc[i][j], 0, 0, 0);
    }
}

// ---------------------------------------------------------------------------
// tiny: conn = sigmoid(relu(na@W1+b1)@W2+b2), wts = softmax(act_w). All f32.
// ---------------------------------------------------------------------------
__global__ __launch_bounds__(256)
void k_small(const float* __restrict__ na, const float* __restrict__ W1,
             const float* __restrict__ b1, const float* __restrict__ W2,
             const float* __restrict__ b2, const float* __restrict__ actw,
             float* __restrict__ conn, float* __restrict__ wts)
{
    __shared__ float red[256 * 32];
    __shared__ float hsh[32];
    const int tid = threadIdx.x;
    float h[32];
#pragma unroll
    for (int k = 0; k < 32; k++) h[k] = 0.f;
    for (int u = tid; u < 2048; u += 256) {
        float nav = na[u];
        const float* row = W1 + u * 32;
#pragma unroll
        for (int k = 0; k < 32; k++) h[k] += nav * row[k];
    }
#pragma unroll
    for (int k = 0; k < 32; k++) red[tid * 32 + k] = h[k];
    for (int s = 128; s > 0; s >>= 1) {
        __syncthreads();
        if (tid < s)
#pragma unroll
            for (int k = 0; k < 32; k++) red[tid * 32 + k] += red[(tid + s) * 32 + k];
    }
    __syncthreads();
    if (tid < 32) hsh[tid] = fmaxf(red[tid] + b1[tid], 0.f);
    if (tid == 0) {
        float e[9], m = -1e30f;
        for (int i = 0; i < 9; i++) { e[i] = actw[i]; m = fmaxf(m, e[i]); }
        float s = 0.f;
        for (int i = 0; i < 9; i++) { e[i] = expf(e[i] - m); s += e[i]; }
        for (int i = 0; i < 9; i++) wts[i] = e[i] / s;
    }
    __syncthreads();
    for (int u = tid; u < 2048; u += 256) {
        float a = 0.f;
#pragma unroll
        for (int k = 0; k < 32; k++) a += hsh[k] * W2[k * 2048 + u];
        conn[u] = 1.f / (1.f + expf(-(a + b2[u])));
    }
}

// ---------------------------------------------------------------------------
// gate softmax + y = x*gate (bf16 out). One wave per row n.
// y[n, d*4+p] = x[n,d]*gate[n,p]
// ---------------------------------------------------------------------------
__global__ __launch_bounds__(256)
void k_gate_y(const float* __restrict__ x, const float* __restrict__ gW,
              const float* __restrict__ gb, float* __restrict__ gate,
              u16* __restrict__ y)
{
    const int tid = threadIdx.x, lane = tid & 63, wv = tid >> 6;
    const int n = blockIdx.x * 4 + wv;
    const float* xr = x + (size_t)n * 1024;
    float a0 = 0, a1 = 0, a2 = 0, a3 = 0;
    float xv[16];
#pragma unroll
    for (int s = 0; s < 16; s++) {
        int d = s * 64 + lane;
        float xd = xr[d]; xv[s] = xd;
        float4 g4 = *(const float4*)(gW + d * 4);
        a0 += xd * g4.x; a1 += xd * g4.y; a2 += xd * g4.z; a3 += xd * g4.w;
    }
#pragma unroll
    for (int off = 32; off > 0; off >>= 1) {
        a0 += __shfl_xor(a0, off); a1 += __shfl_xor(a1, off);
        a2 += __shfl_xor(a2, off); a3 += __shfl_xor(a3, off);
    }
    a0 += gb[0]; a1 += gb[1]; a2 += gb[2]; a3 += gb[3];
    float m = fmaxf(fmaxf(a0, a1), fmaxf(a2, a3));
    float e0 = expf(a0 - m), e1 = expf(a1 - m), e2 = expf(a2 - m), e3 = expf(a3 - m);
    float inv = 1.f / (e0 + e1 + e2 + e3);
    float g0 = e0 * inv, g1 = e1 * inv, g2 = e2 * inv, g3 = e3 * inv;
    if (lane == 0) *(float4*)(gate + n * 4) = make_float4(g0, g1, g2, g3);
#pragma unroll
    for (int s = 0; s < 16; s++) {
        int d = s * 64 + lane;
        ushort4 o;
        o.x = f2b(xv[s] * g0); o.y = f2b(xv[s] * g1);
        o.z = f2b(xv[s] * g2); o.w = f2b(xv[s] * g3);
        *(ushort4*)(y + (size_t)n * 4096 + d * 4) = o;
    }
}

// ---------------------------------------------------------------------------
// wmT[u, d*4+b] = w[d,u,b] * sigmoid(delay[d,u,b]); f32 in, bf16 out.
// ---------------------------------------------------------------------------
__global__ __launch_bounds__(256)
void k_wmT(const float* __restrict__ w, const float* __restrict__ delay,
           u16* __restrict__ wmT)
{
    __shared__ __align__(16) ushort4 tile[32][65];
    const int tid = threadIdx.x;
    const int tx = tid & 63, ty = tid >> 6;          // tx: u, ty: d-subset
    const int u0 = blockIdx.x * 64, d0 = blockIdx.y * 32;
#pragma unroll
    for (int i = 0; i < 8; i++) {
        int d = i * 4 + ty;
        size_t idx = ((size_t)(d0 + d) * 2048 + (u0 + tx)) * 4;
        float4 w4 = *(const float4*)(w + idx);
        float4 d4 = *(const float4*)(delay + idx);
        ushort4 o;
        o.x = f2b(w4.x / (1.f + expf(-d4.x)));
        o.y = f2b(w4.y / (1.f + expf(-d4.y)));
        o.z = f2b(w4.z / (1.f + expf(-d4.z)));
        o.w = f2b(w4.w / (1.f + expf(-d4.w)));
        tile[d][tx] = o;
    }
    __syncthreads();
    const int dx = tid & 31, uy = tid >> 5;
#pragma unroll
    for (int i = 0; i < 8; i++) {
        int u = i * 8 + uy;
        *(ushort4*)(wmT + (size_t)(u0 + u) * 4096 + (d0 + dx) * 4) = tile[dx][u];
    }
}

// ---------------------------------------------------------------------------
// transpose + cast: in[R,C] f32 -> out[C,R] bf16, 64x64 tiles
// ---------------------------------------------------------------------------
__global__ __launch_bounds__(256)
void k_transpose(const float* __restrict__ in, u16* __restrict__ out, int R, int C)
{
    __shared__ __align__(16) u16 t[64][68];
    const int tid = threadIdx.x, tx = tid & 15, ty = tid >> 4;
    const int c0 = blockIdx.x * 64, r0 = blockIdx.y * 64;
#pragma unroll
    for (int i = 0; i < 4; i++) {
        int r = r0 + ty + i * 16;
        float4 v = *(const float4*)(in + (size_t)r * C + c0 + tx * 4);
        t[tx * 4 + 0][ty + i * 16] = f2b(v.x); t[tx * 4 + 1][ty + i * 16] = f2b(v.y);
        t[tx * 4 + 2][ty + i * 16] = f2b(v.z); t[tx * 4 + 3][ty + i * 16] = f2b(v.w);
    }
    __syncthreads();
#pragma unroll
    for (int i = 0; i < 4; i++) {
        int c = ty + i * 16;
        ushort4 v;
        v.x = t[c][tx * 4 + 0]; v.y = t[c][tx * 4 + 1];
        v.z = t[c][tx * 4 + 2]; v.w = t[c][tx * 4 + 3];
        *(ushort4*)(out + (size_t)(c0 + c) * R + r0 + tx * 4) = v;
    }
}

// ---------------------------------------------------------------------------
// 8-way activation blend
// ---------------------------------------------------------------------------
__device__ __forceinline__ float act_blend(float a,
    float w0, float w1, float w2, float w3,
    float w4, float w5, float w6, float w7)
{
    float sig = 1.f / (1.f + expf(-a));
    float elu = (a > 0.f) ? a : (expf(a) - 1.f);
    float th  = tanhf(a);
    float rel = fmaxf(a, 0.f);
    float sil = a * sig;
    float gel = a * 0.5f * (1.f + erff(a * 0.70710678118654752f));
    float sel = (a > 0.f) ? 1.0507009873554805f * a
                          : 1.0507009873554805f * 1.6732632423543772f * (expf(a) - 1.f);
    float sp  = (a > 20.f) ? a : log1pf(expf(a));
    float mish = a * tanhf(sp);
    return w0 * sig + w1 * elu + w2 * th + w3 * rel + w4 * sil + w5 * gel
         + w6 * sel + w7 * mish;
}

// ---------------------------------------------------------------------------
// GEMM-A: blend[n,u] = blend8(relu((y@wmT^T + b·gate)[n,u]*conn[u]*mask[u]))
// BM=128, BN=64 -> grid (2048/64, 2048/128) = (32,16) = 512 blocks (2/CU)
// ---------------------------------------------------------------------------
template<int BM, int BN>
__global__ __launch_bounds__(256, 4)
void k_gemm_blend(const u16* __restrict__ Y, const u16* __restrict__ WMT,
                  const float* __restrict__ gate, const float* __restrict__ conn,
                  const float* __restrict__ wts,
                  const float* __restrict__ bbias, const float* __restrict__ mask,
                  u16* __restrict__ blend)
{
    constexpr int MT = BM / 32, NT = BN / 32;
    __shared__ __align__(16) u16 smem[(BM + BN) * 32];
    f32x4 acc[MT][NT];
    const int row0 = blockIdx.y * BM, col0 = blockIdx.x * BN;
    gemm_core<BM, BN>(Y, WMT, 4096, row0, col0, smem, smem + BM * 32, acc);

    const int tid = threadIdx.x, lane = tid & 63, wv = tid >> 6;
    const int wr = wv >> 1, wc = wv & 1, lr = lane & 15, kg = lane >> 4;
    const float w0 = wts[0], w1 = wts[1], w2 = wts[2], w3 = wts[3];
    const float w4 = wts[4], w5 = wts[5], w6 = wts[6], w7 = wts[7];

    float cm[NT], bb0[NT], bb1[NT], bb2[NT], bb3[NT];
    int uu[NT];
#pragma unroll
    for (int j = 0; j < NT; j++) {
        int u = col0 + wc * (BN / 2) + j * 16 + lr;
        uu[j] = u;
        cm[j] = conn[u] * mask[u];
        float4 b4 = *(const float4*)(bbias + u * 4);
        bb0[j] = b4.x; bb1[j] = b4.y; bb2[j] = b4.z; bb3[j] = b4.w;
    }
#pragma unroll
    for (int i = 0; i < MT; i++) {
#pragma unroll
        for (int r = 0; r < 4; r++) {
            int n = row0 + wr * (BM / 2) + i * 16 + kg * 4 + r;
            float4 g = *(const float4*)(gate + n * 4);
            size_t ob = (size_t)n * 2048;
#pragma unroll
            for (int j = 0; j < NT; j++) {
                float z = acc[i][j][r] + g.x * bb0[j] + g.y * bb1[j]
                                       + g.z * bb2[j] + g.w * bb3[j];
                float a = fmaxf(z * cm[j], 0.f);
                blend[ob + uu[j]] = f2b(act_blend(a, w0, w1, w2, w3, w4, w5, w6, w7));
            }
        }
    }
}

// ---------------------------------------------------------------------------
// GEMM-B: logits[n,m] = blend@read_W + read_b (bf16 out; softmaxed in place)
// 128x128, grid (64,16) = 1024 blocks (4/CU) — proven m97 config
// ---------------------------------------------------------------------------
__global__ __launch_bounds__(256, 2)
void k_gemm_logits(const u16* __restrict__ BL, const u16* __restrict__ RWT,
                   const float* __restrict__ rbias, u16* __restrict__ out)
{
    __shared__ __align__(16) u16 smem[(128 + 128) * 32];
    f32x4 acc[4][4];
    const int row0 = blockIdx.y * 128, col0 = blockIdx.x * 128;
    gemm_core<128, 128>(BL, RWT, 2048, row0, col0, smem, smem + 128 * 32, acc);

    const int tid = threadIdx.x, lane = tid & 63, wv = tid >> 6;
    const int wr = wv >> 1, wc = wv & 1, lr = lane & 15, kg = lane >> 4;
    float rb[4]; int mm[4];
#pragma unroll
    for (int j = 0; j < 4; j++) {
        mm[j] = col0 + wc * 64 + j * 16 + lr;
        rb[j] = rbias[mm[j]];
    }
#pragma unroll
    for (int i = 0; i < 4; i++)
#pragma unroll
        for (int r = 0; r < 4; r++) {
            int n = row0 + wr * 64 + i * 16 + kg * 4 + r;
            size_t ob = (size_t)n * 8192;
#pragma unroll
            for (int j = 0; j < 4; j++)
                out[ob + mm[j]] = f2b(acc[i][j][r] + rb[j]);
        }
}

// ---------------------------------------------------------------------------
// in-place row softmax over 8192 bf16 (one block per row, values in registers)
// ---------------------------------------------------------------------------
__global__ __launch_bounds__(256)
void k_softmax(u16* __restrict__ buf)
{
    __shared__ float red[8];
    const int tid = threadIdx.x, lane = tid & 63, wv = tid >> 6;
    u16* row = buf + (size_t)blockIdx.x * 8192;
    float v[32];
    float mx = -1e30f;
#pragma unroll
    for (int s = 0; s < 8; s++) {
        ushort4 u4 = *(const ushort4*)(row + (s * 256 + tid) * 4);
        float a = b2f(u4.x), b = b2f(u4.y), c = b2f(u4.z), d = b2f(u4.w);
        v[s * 4 + 0] = a; v[s * 4 + 1] = b; v[s * 4 + 2] = c; v[s * 4 + 3] = d;
        mx = fmaxf(mx, fmaxf(fmaxf(a, b), fmaxf(c, d)));
    }
#pragma unroll
    for (int off = 32; off > 0; off >>= 1) mx = fmaxf(mx, __shfl_xor(mx, off));
    if (lane == 0) red[wv] = mx;
    __syncthreads();
    mx = fmaxf(fmaxf(red[0], red[1]), fmaxf(red[2], red[3]));
    float sum = 0.f;
#pragma unroll
    for (int k = 0; k < 32; k++) { v[k] = expf(v[k] - mx); sum += v[k]; }
#pragma unroll
    for (int off = 32; off > 0; off >>= 1) sum += __shfl_xor(sum, off);
    if (lane == 0) red[4 + wv] = sum;
    __syncthreads();
    float inv = 1.f / (red[4] + red[5] + red[6] + red[7]);
#pragma unroll
    for (int s = 0; s < 8; s++) {
        ushort4 o;
        o.x = f2b(v[s * 4 + 0] * inv); o.y = f2b(v[s * 4 + 1] * inv);
        o.z = f2b(v[s * 4 + 2] * inv); o.w = f2b(v[s * 4 + 3] * inv);
        *(ushort4*)(row + (s * 256 + tid) * 4) = o;
    }
}

// ---------------------------------------------------------------------------
// GEMM-C: out[n,md] = attn @ memory, f32 out.
// BM=64, BN=64 -> grid (1024/64, 2048/64) = (16,32) = 512 blocks (2/CU)
// ---------------------------------------------------------------------------
template<int BM, int BN>
__global__ __launch_bounds__(256, 4)
void k_gemm_out(const u16* __restrict__ AT, const u16* __restrict__ MEMT,
                float* __restrict__ out)
{
    constexpr int MT = BM / 32, NT = BN / 32;
    __shared__ __align__(16) u16 smem[(BM + BN) * 32];
    f32x4 acc[MT][NT];
    const int row0 = blockIdx.y * BM, col0 = blockIdx.x * BN;
    gemm_core<BM, BN>(AT, MEMT, 8192, row0, col0, smem, smem + BM * 32, acc);

    const int tid = threadIdx.x, lane = tid & 63, wv = tid >> 6;
    const int wr = wv >> 1, wc = wv & 1, lr = lane & 15, kg = lane >> 4;
    int mm[NT];
#pragma unroll
    for (int j = 0; j < NT; j++) mm[j] = col0 + wc * (BN / 2) + j * 16 + lr;
#pragma unroll
    for (int i = 0; i < MT; i++)
#pragma unroll
        for (int r = 0; r < 4; r++) {
            int n = row0 + wr * (BM / 2) + i * 16 + kg * 4 + r;
            size_t ob = (size_t)n * 1024;
#pragma unroll
            for (int j = 0; j < NT; j++)
                out[ob + mm[j]] = acc[i][j][r];
        }
}

// sentinel: distinctive output if workspace is too small (absmax ~12345)
__global__ void k_fill(float* out, int n)
{
    int i = blockIdx.x * 256 + threadIdx.x;
    if (i < n) out[i] = 12345.f;
}

// ---------------------------------------------------------------------------
extern "C" void kernel_launch(void* const* d_in, const int* in_sizes, int n_in,
                              void* d_out, int out_size, void* d_ws, size_t ws_size,
                              hipStream_t stream)
{
    const float* x     = (const float*)d_in[0];
    const float* w     = (const float*)d_in[1];
    const float* delay = (const float*)d_in[2];
    const float* bb    = (const float*)d_in[3];
    const float* gW    = (const float*)d_in[4];
    const float* gb    = (const float*)d_in[5];
    const float* na    = (const float*)d_in[6];
    const float* cW1   = (const float*)d_in[7];
    const float* cb1   = (const float*)d_in[8];
    const float* cW2   = (const float*)d_in[9];
    const float* cb2   = (const float*)d_in[10];
    const float* mask  = (const float*)d_in[11];
    const float* actw  = (const float*)d_in[12];
    const float* rW    = (const float*)d_in[13];
    const float* rb    = (const float*)d_in[14];
    const float* mem   = (const float*)d_in[15];
    (void)in_sizes; (void)n_in;

    char* ws = (char*)d_ws;
    size_t off = 0;
    auto alloc = [&](size_t bytes) {
        size_t o = off; off += (bytes + 255) & ~(size_t)255; return o;
    };
    size_t o_wts   = alloc(9 * 4);
    size_t o_gate  = alloc(2048 * 4 * 4);
    size_t o_conn  = alloc(2048 * 4);
    size_t o_y     = alloc((size_t)2048 * 4096 * 2);   // later aliased as memT
    size_t o_wmT   = alloc((size_t)2048 * 4096 * 2);
    size_t o_blend = alloc((size_t)2048 * 2048 * 2);
    size_t o_rwT   = alloc((size_t)8192 * 2048 * 2);
    size_t o_log   = alloc((size_t)2048 * 8192 * 2);   // logits, then attn in-place

    if (off > ws_size) {   // loud, distinguishable failure mode
        k_fill<<<(out_size + 255) / 256, 256, 0, stream>>>((float*)d_out, out_size);
        return;
    }

    float* wts   = (float*)(ws + o_wts);
    float* gate  = (float*)(ws + o_gate);
    float* conn  = (float*)(ws + o_conn);
    u16* y       = (u16*)(ws + o_y);
    u16* wmT     = (u16*)(ws + o_wmT);
    u16* blend   = (u16*)(ws + o_blend);
    u16* rwT     = (u16*)(ws + o_rwT);
    u16* logits  = (u16*)(ws + o_log);
    u16* memT    = y;   // y dead after k_gemm_blend; same size (16 MB)

    k_small<<<1, 256, 0, stream>>>(na, cW1, cb1, cW2, cb2, actw, conn, wts);
    k_gate_y<<<512, 256, 0, stream>>>(x, gW, gb, gate, y);
    k_wmT<<<dim3(32, 32), 256, 0, stream>>>(w, delay, wmT);
    k_gemm_blend<128, 64><<<dim3(32, 16), 256, 0, stream>>>(y, wmT, gate, conn, wts, bb, mask, blend);
    k_transpose<<<dim3(128, 32), 256, 0, stream>>>(rW, rwT, 2048, 8192);
    k_gemm_logits<<<dim3(64, 16), 256, 0, stream>>>(blend, rwT, rb, logits);
    k_softmax<<<2048, 256, 0, stream>>>(logits);
    k_transpose<<<dim3(16, 128), 256, 0, stream>>>(mem, memT, 8192, 1024);
    k_gemm_out<64, 64><<<dim3(16, 32), 256, 0, stream>>>(logits, memT, (float*)d_out);
}

// Round 6
// 499.822 us; speedup vs baseline: 1.1744x; 1.0632x over previous
//
#include <hip/hip_runtime.h>

// ============================================================================
// PlasticityModelMoE — MI355X (gfx950). Inputs f32, output f32, bf16 MFMA.
// R6: GEMM-A/C stage TWO BK=32 tiles per barrier window (K-step 64, split
// stage buffers) — halves barrier count without changing the per-buffer LDS
// layout (BK=64 row stride would cause same-bank ds_read collisions, m132).
// GEMM-B stays at proven 128x128/BK=32, 4 blocks/CU.
// ============================================================================

typedef unsigned short u16;
typedef __attribute__((ext_vector_type(8))) short bf16x8;   // 8 bf16 = 4 VGPRs
typedef __attribute__((ext_vector_type(4))) float f32x4;

__device__ __forceinline__ float b2f(u16 h) {
    union { unsigned u; float f; } v; v.u = ((unsigned)h) << 16; return v.f;
}
__device__ __forceinline__ u16 f2b(float f) {
    union { float f; unsigned u; } v; v.f = f;
    unsigned u = v.u;
    return (u16)((u + 0x7fffu + ((u >> 16) & 1u)) >> 16);   // round-nearest-even
}

// async global->LDS, 16B per lane (wave-uniform base + lane*16 — m97 pattern).
__device__ __forceinline__ void async_copy16(void* lds, const void* g) {
    __builtin_amdgcn_global_load_lds(
        (__attribute__((address_space(1))) void*)(g),
        (__attribute__((address_space(3))) void*)(lds), 16, 0, 0);
}

// ---------------------------------------------------------------------------
// GEMM core (BK=32, 1 stage / barrier): C[M,N] += A[M,K]*B[N,K]^T.
// 256 thr, 4 waves 2x2, wave tile (BM/2)x(BN/2), mfma_f32_16x16x32_bf16.
// Layouts (m89/m91): A-frag A[m=lane&15][k=(lane>>4)*8+j]; B-frag same (n);
// C/D col(n)=lane&15, row(m)=(lane>>4)*4+reg.
// ---------------------------------------------------------------------------
template<int BM, int BN>
__device__ __forceinline__ void gemm_core(const u16* __restrict__ A,
                                          const u16* __restrict__ B,
                                          int K, int row0, int col0,
                                          u16* sA, u16* sB,
                                          f32x4 (&acc)[BM / 32][BN / 32])
{
    constexpr int MT = BM / 32, NT = BN / 32;
    const int tid  = threadIdx.x;
    const int lane = tid & 63;
    const int wv   = tid >> 6;
    const int wr   = wv >> 1, wc = wv & 1;
    const int lr   = lane & 15, kg = lane >> 4;

#pragma unroll
    for (int i = 0; i < MT; i++)
#pragma unroll
        for (int j = 0; j < NT; j++) {
            f32x4 z = {0.f, 0.f, 0.f, 0.f};
            acc[i][j] = z;
        }

    for (int k0 = 0; k0 < K; k0 += 32) {
        __syncthreads();
#pragma unroll
        for (int c = tid; c < BM * 4; c += 256)
            async_copy16(sA + c * 8,
                         A + (size_t)(row0 + (c >> 2)) * K + k0 + (c & 3) * 8);
#pragma unroll
        for (int c = tid; c < BN * 4; c += 256)
            async_copy16(sB + c * 8,
                         B + (size_t)(col0 + (c >> 2)) * K + k0 + (c & 3) * 8);
        __syncthreads();   // drains vmcnt (global_load_lds)

        bf16x8 af[MT], bfr[NT];
#pragma unroll
        for (int i = 0; i < MT; i++)
            af[i] = *(const bf16x8*)(sA + ((wr * (BM / 2) + i * 16 + lr) * 32 + kg * 8));
#pragma unroll
        for (int j = 0; j < NT; j++)
            bfr[j] = *(const bf16x8*)(sB + ((wc * (BN / 2) + j * 16 + lr) * 32 + kg * 8));
#pragma unroll
        for (int i = 0; i < MT; i++)
#pragma unroll
            for (int j = 0; j < NT; j++)
                acc[i][j] = __builtin_amdgcn_mfma_f32_16x16x32_bf16(
                                af[i], bfr[j], acc[i][j], 0, 0, 0);
    }
}

// ---------------------------------------------------------------------------
// GEMM core v2 (K-step 64 = two BK=32 stages per barrier window).
// Same per-buffer layout/addressing as gemm_core; requires K % 64 == 0.
// ---------------------------------------------------------------------------
template<int BM, int BN>
__device__ __forceinline__ void gemm_core2(const u16* __restrict__ A,
                                           const u16* __restrict__ B,
                                           int K, int row0, int col0,
                                           u16* sA0, u16* sB0,
                                           u16* sA1, u16* sB1,
                                           f32x4 (&acc)[BM / 32][BN / 32])
{
    constexpr int MT = BM / 32, NT = BN / 32;
    const int tid  = threadIdx.x;
    const int lane = tid & 63;
    const int wv   = tid >> 6;
    const int wr   = wv >> 1, wc = wv & 1;
    const int lr   = lane & 15, kg = lane >> 4;

#pragma unroll
    for (int i = 0; i < MT; i++)
#pragma unroll
        for (int j = 0; j < NT; j++) {
            f32x4 z = {0.f, 0.f, 0.f, 0.f};
            acc[i][j] = z;
        }

    for (int k0 = 0; k0 < K; k0 += 64) {
        __syncthreads();
#pragma unroll
        for (int c = tid; c < BM * 4; c += 256) {
            const u16* gA = A + (size_t)(row0 + (c >> 2)) * K + k0 + (c & 3) * 8;
            async_copy16(sA0 + c * 8, gA);
            async_copy16(sA1 + c * 8, gA + 32);
        }
#pragma unroll
        for (int c = tid; c < BN * 4; c += 256) {
            const u16* gB = B + (size_t)(col0 + (c >> 2)) * K + k0 + (c & 3) * 8;
            async_copy16(sB0 + c * 8, gB);
            async_copy16(sB1 + c * 8, gB + 32);
        }
        __syncthreads();   // drains vmcnt for all 2x staging loads

        bf16x8 af[MT], bfr[NT];
        // stage 0
#pragma unroll
        for (int i = 0; i < MT; i++)
            af[i] = *(const bf16x8*)(sA0 + ((wr * (BM / 2) + i * 16 + lr) * 32 + kg * 8));
#pragma unroll
        for (int j = 0; j < NT; j++)
            bfr[j] = *(const bf16x8*)(sB0 + ((wc * (BN / 2) + j * 16 + lr) * 32 + kg * 8));
#pragma unroll
        for (int i = 0; i < MT; i++)
#pragma unroll
            for (int j = 0; j < NT; j++)
                acc[i][j] = __builtin_amdgcn_mfma_f32_16x16x32_bf16(
                                af[i], bfr[j], acc[i][j], 0, 0, 0);
        // stage 1
#pragma unroll
        for (int i = 0; i < MT; i++)
            af[i] = *(const bf16x8*)(sA1 + ((wr * (BM / 2) + i * 16 + lr) * 32 + kg * 8));
#pragma unroll
        for (int j = 0; j < NT; j++)
            bfr[j] = *(const bf16x8*)(sB1 + ((wc * (BN / 2) + j * 16 + lr) * 32 + kg * 8));
#pragma unroll
        for (int i = 0; i < MT; i++)
#pragma unroll
            for (int j = 0; j < NT; j++)
                acc[i][j] = __builtin_amdgcn_mfma_f32_16x16x32_bf16(
                                af[i], bfr[j], acc[i][j], 0, 0, 0);
    }
}

// ---------------------------------------------------------------------------
// tiny: conn = sigmoid(relu(na@W1+b1)@W2+b2), wts = softmax(act_w). All f32.
// ---------------------------------------------------------------------------
__global__ __launch_bounds__(256)
void k_small(const float* __restrict__ na, const float* __restrict__ W1,
             const float* __restrict__ b1, const float* __restrict__ W2,
             const float* __restrict__ b2, const float* __restrict__ actw,
             float* __restrict__ conn, float* __restrict__ wts)
{
    __shared__ float red[256 * 32];
    __shared__ float hsh[32];
    const int tid = threadIdx.x;
    float h[32];
#pragma unroll
    for (int k = 0; k < 32; k++) h[k] = 0.f;
    for (int u = tid; u < 2048; u += 256) {
        float nav = na[u];
        const float* row = W1 + u * 32;
#pragma unroll
        for (int k = 0; k < 32; k++) h[k] += nav * row[k];
    }
#pragma unroll
    for (int k = 0; k < 32; k++) red[tid * 32 + k] = h[k];
    for (int s = 128; s > 0; s >>= 1) {
        __syncthreads();
        if (tid < s)
#pragma unroll
            for (int k = 0; k < 32; k++) red[tid * 32 + k] += red[(tid + s) * 32 + k];
    }
    __syncthreads();
    if (tid < 32) hsh[tid] = fmaxf(red[tid] + b1[tid], 0.f);
    if (tid == 0) {
        float e[9], m = -1e30f;
        for (int i = 0; i < 9; i++) { e[i] = actw[i]; m = fmaxf(m, e[i]); }
        float s = 0.f;
        for (int i = 0; i < 9; i++) { e[i] = expf(e[i] - m); s += e[i]; }
        for (int i = 0; i < 9; i++) wts[i] = e[i] / s;
    }
    __syncthreads();
    for (int u = tid; u < 2048; u += 256) {
        float a = 0.f;
#pragma unroll
        for (int k = 0; k < 32; k++) a += hsh[k] * W2[k * 2048 + u];
        conn[u] = 1.f / (1.f + expf(-(a + b2[u])));
    }
}

// ---------------------------------------------------------------------------
// gate softmax + y = x*gate (bf16 out). One wave per row n.
// ---------------------------------------------------------------------------
__global__ __launch_bounds__(256)
void k_gate_y(const float* __restrict__ x, const float* __restrict__ gW,
              const float* __restrict__ gb, float* __restrict__ gate,
              u16* __restrict__ y)
{
    const int tid = threadIdx.x, lane = tid & 63, wv = tid >> 6;
    const int n = blockIdx.x * 4 + wv;
    const float* xr = x + (size_t)n * 1024;
    float a0 = 0, a1 = 0, a2 = 0, a3 = 0;
    float xv[16];
#pragma unroll
    for (int s = 0; s < 16; s++) {
        int d = s * 64 + lane;
        float xd = xr[d]; xv[s] = xd;
        float4 g4 = *(const float4*)(gW + d * 4);
        a0 += xd * g4.x; a1 += xd * g4.y; a2 += xd * g4.z; a3 += xd * g4.w;
    }
#pragma unroll
    for (int off = 32; off > 0; off >>= 1) {
        a0 += __shfl_xor(a0, off); a1 += __shfl_xor(a1, off);
        a2 += __shfl_xor(a2, off); a3 += __shfl_xor(a3, off);
    }
    a0 += gb[0]; a1 += gb[1]; a2 += gb[2]; a3 += gb[3];
    float m = fmaxf(fmaxf(a0, a1), fmaxf(a2, a3));
    float e0 = expf(a0 - m), e1 = expf(a1 - m), e2 = expf(a2 - m), e3 = expf(a3 - m);
    float inv = 1.f / (e0 + e1 + e2 + e3);
    float g0 = e0 * inv, g1 = e1 * inv, g2 = e2 * inv, g3 = e3 * inv;
    if (lane == 0) *(float4*)(gate + n * 4) = make_float4(g0, g1, g2, g3);
#pragma unroll
    for (int s = 0; s < 16; s++) {
        int d = s * 64 + lane;
        ushort4 o;
        o.x = f2b(xv[s] * g0); o.y = f2b(xv[s] * g1);
        o.z = f2b(xv[s] * g2); o.w = f2b(xv[s] * g3);
        *(ushort4*)(y + (size_t)n * 4096 + d * 4) = o;
    }
}

// ---------------------------------------------------------------------------
// wmT[u, d*4+b] = w[d,u,b] * sigmoid(delay[d,u,b]); f32 in, bf16 out.
// ---------------------------------------------------------------------------
__global__ __launch_bounds__(256)
void k_wmT(const float* __restrict__ w, const float* __restrict__ delay,
           u16* __restrict__ wmT)
{
    __shared__ __align__(16) ushort4 tile[32][65];
    const int tid = threadIdx.x;
    const int tx = tid & 63, ty = tid >> 6;          // tx: u, ty: d-subset
    const int u0 = blockIdx.x * 64, d0 = blockIdx.y * 32;
#pragma unroll
    for (int i = 0; i < 8; i++) {
        int d = i * 4 + ty;
        size_t idx = ((size_t)(d0 + d) * 2048 + (u0 + tx)) * 4;
        float4 w4 = *(const float4*)(w + idx);
        float4 d4 = *(const float4*)(delay + idx);
        ushort4 o;
        o.x = f2b(w4.x / (1.f + expf(-d4.x)));
        o.y = f2b(w4.y / (1.f + expf(-d4.y)));
        o.z = f2b(w4.z / (1.f + expf(-d4.z)));
        o.w = f2b(w4.w / (1.f + expf(-d4.w)));
        tile[d][tx] = o;
    }
    __syncthreads();
    const int dx = tid & 31, uy = tid >> 5;
#pragma unroll
    for (int i = 0; i < 8; i++) {
        int u = i * 8 + uy;
        *(ushort4*)(wmT + (size_t)(u0 + u) * 4096 + (d0 + dx) * 4) = tile[dx][u];
    }
}

// ---------------------------------------------------------------------------
// transpose + cast: in[R,C] f32 -> out[C,R] bf16, 64x64 tiles
// ---------------------------------------------------------------------------
__global__ __launch_bounds__(256)
void k_transpose(const float* __restrict__ in, u16* __restrict__ out, int R, int C)
{
    __shared__ __align__(16) u16 t[64][68];
    const int tid = threadIdx.x, tx = tid & 15, ty = tid >> 4;
    const int c0 = blockIdx.x * 64, r0 = blockIdx.y * 64;
#pragma unroll
    for (int i = 0; i < 4; i++) {
        int r = r0 + ty + i * 16;
        float4 v = *(const float4*)(in + (size_t)r * C + c0 + tx * 4);
        t[tx * 4 + 0][ty + i * 16] = f2b(v.x); t[tx * 4 + 1][ty + i * 16] = f2b(v.y);
        t[tx * 4 + 2][ty + i * 16] = f2b(v.z); t[tx * 4 + 3][ty + i * 16] = f2b(v.w);
    }
    __syncthreads();
#pragma unroll
    for (int i = 0; i < 4; i++) {
        int c = ty + i * 16;
        ushort4 v;
        v.x = t[c][tx * 4 + 0]; v.y = t[c][tx * 4 + 1];
        v.z = t[c][tx * 4 + 2]; v.w = t[c][tx * 4 + 3];
        *(ushort4*)(out + (size_t)(c0 + c) * R + r0 + tx * 4) = v;
    }
}

// ---------------------------------------------------------------------------
// 8-way activation blend
// ---------------------------------------------------------------------------
__device__ __forceinline__ float act_blend(float a,
    float w0, float w1, float w2, float w3,
    float w4, float w5, float w6, float w7)
{
    float sig = 1.f / (1.f + expf(-a));
    float elu = (a > 0.f) ? a : (expf(a) - 1.f);
    float th  = tanhf(a);
    float rel = fmaxf(a, 0.f);
    float sil = a * sig;
    float gel = a * 0.5f * (1.f + erff(a * 0.70710678118654752f));
    float sel = (a > 0.f) ? 1.0507009873554805f * a
                          : 1.0507009873554805f * 1.6732632423543772f * (expf(a) - 1.f);
    float sp  = (a > 20.f) ? a : log1pf(expf(a));
    float mish = a * tanhf(sp);
    return w0 * sig + w1 * elu + w2 * th + w3 * rel + w4 * sil + w5 * gel
         + w6 * sel + w7 * mish;
}

// ---------------------------------------------------------------------------
// GEMM-A: blend[n,u] = blend8(relu((y@wmT^T + b·gate)[n,u]*conn[u]*mask[u]))
// BM=128, BN=64, K-step 64 -> grid (32,16) = 512 blocks (2/CU), LDS 24 KB
// ---------------------------------------------------------------------------
template<int BM, int BN>
__global__ __launch_bounds__(256, 4)
void k_gemm_blend(const u16* __restrict__ Y, const u16* __restrict__ WMT,
                  const float* __restrict__ gate, const float* __restrict__ conn,
                  const float* __restrict__ wts,
                  const float* __restrict__ bbias, const float* __restrict__ mask,
                  u16* __restrict__ blend)
{
    constexpr int MT = BM / 32, NT = BN / 32;
    __shared__ __align__(16) u16 smem[2 * (BM + BN) * 32];
    f32x4 acc[MT][NT];
    const int row0 = blockIdx.y * BM, col0 = blockIdx.x * BN;
    u16* sA0 = smem;
    u16* sB0 = sA0 + BM * 32;
    u16* sA1 = sB0 + BN * 32;
    u16* sB1 = sA1 + BM * 32;
    gemm_core2<BM, BN>(Y, WMT, 4096, row0, col0, sA0, sB0, sA1, sB1, acc);

    const int tid = threadIdx.x, lane = tid & 63, wv = tid >> 6;
    const int wr = wv >> 1, wc = wv & 1, lr = lane & 15, kg = lane >> 4;
    const float w0 = wts[0], w1 = wts[1], w2 = wts[2], w3 = wts[3];
    const float w4 = wts[4], w5 = wts[5], w6 = wts[6], w7 = wts[7];

    float cm[NT], bb0[NT], bb1[NT], bb2[NT], bb3[NT];
    int uu[NT];
#pragma unroll
    for (int j = 0; j < NT; j++) {
        int u = col0 + wc * (BN / 2) + j * 16 + lr;
        uu[j] = u;
        cm[j] = conn[u] * mask[u];
        float4 b4 = *(const float4*)(bbias + u * 4);
        bb0[j] = b4.x; bb1[j] = b4.y; bb2[j] = b4.z; bb3[j] = b4.w;
    }
#pragma unroll
    for (int i = 0; i < MT; i++) {
#pragma unroll
        for (int r = 0; r < 4; r++) {
            int n = row0 + wr * (BM / 2) + i * 16 + kg * 4 + r;
            float4 g = *(const float4*)(gate + n * 4);
            size_t ob = (size_t)n * 2048;
#pragma unroll
            for (int j = 0; j < NT; j++) {
                float z = acc[i][j][r] + g.x * bb0[j] + g.y * bb1[j]
                                       + g.z * bb2[j] + g.w * bb3[j];
                float a = fmaxf(z * cm[j], 0.f);
                blend[ob + uu[j]] = f2b(act_blend(a, w0, w1, w2, w3, w4, w5, w6, w7));
            }
        }
    }
}

// ---------------------------------------------------------------------------
// GEMM-B: logits[n,m] = blend@read_W + read_b (bf16 out; softmaxed in place)
// 128x128, BK=32, grid (64,16) = 1024 blocks (4/CU) — proven config, unchanged
// ---------------------------------------------------------------------------
__global__ __launch_bounds__(256, 2)
void k_gemm_logits(const u16* __restrict__ BL, const u16* __restrict__ RWT,
                   const float* __restrict__ rbias, u16* __restrict__ out)
{
    __shared__ __align__(16) u16 smem[(128 + 128) * 32];
    f32x4 acc[4][4];
    const int row0 = blockIdx.y * 128, col0 = blockIdx.x * 128;
    gemm_core<128, 128>(BL, RWT, 2048, row0, col0, smem, smem + 128 * 32, acc);

    const int tid = threadIdx.x, lane = tid & 63, wv = tid >> 6;
    const int wr = wv >> 1, wc = wv & 1, lr = lane & 15, kg = lane >> 4;
    float rb[4]; int mm[4];
#pragma unroll
    for (int j = 0; j < 4; j++) {
        mm[j] = col0 + wc * 64 + j * 16 + lr;
        rb[j] = rbias[mm[j]];
    }
#pragma unroll
    for (int i = 0; i < 4; i++)
#pragma unroll
        for (int r = 0; r < 4; r++) {
            int n = row0 + wr * 64 + i * 16 + kg * 4 + r;
            size_t ob = (size_t)n * 8192;
#pragma unroll
            for (int j = 0; j < 4; j++)
                out[ob + mm[j]] = f2b(acc[i][j][r] + rb[j]);
        }
}

// ---------------------------------------------------------------------------
// in-place row softmax over 8192 bf16 (one block per row, values in registers)
// ---------------------------------------------------------------------------
__global__ __launch_bounds__(256)
void k_softmax(u16* __restrict__ buf)
{
    __shared__ float red[8];
    const int tid = threadIdx.x, lane = tid & 63, wv = tid >> 6;
    u16* row = buf + (size_t)blockIdx.x * 8192;
    float v[32];
    float mx = -1e30f;
#pragma unroll
    for (int s = 0; s < 8; s++) {
        ushort4 u4 = *(const ushort4*)(row + (s * 256 + tid) * 4);
        float a = b2f(u4.x), b = b2f(u4.y), c = b2f(u4.z), d = b2f(u4.w);
        v[s * 4 + 0] = a; v[s * 4 + 1] = b; v[s * 4 + 2] = c; v[s * 4 + 3] = d;
        mx = fmaxf(mx, fmaxf(fmaxf(a, b), fmaxf(c, d)));
    }
#pragma unroll
    for (int off = 32; off > 0; off >>= 1) mx = fmaxf(mx, __shfl_xor(mx, off));
    if (lane == 0) red[wv] = mx;
    __syncthreads();
    mx = fmaxf(fmaxf(red[0], red[1]), fmaxf(red[2], red[3]));
    float sum = 0.f;
#pragma unroll
    for (int k = 0; k < 32; k++) { v[k] = expf(v[k] - mx); sum += v[k]; }
#pragma unroll
    for (int off = 32; off > 0; off >>= 1) sum += __shfl_xor(sum, off);
    if (lane == 0) red[4 + wv] = sum;
    __syncthreads();
    float inv = 1.f / (red[4] + red[5] + red[6] + red[7]);
#pragma unroll
    for (int s = 0; s < 8; s++) {
        ushort4 o;
        o.x = f2b(v[s * 4 + 0] * inv); o.y = f2b(v[s * 4 + 1] * inv);
        o.z = f2b(v[s * 4 + 2] * inv); o.w = f2b(v[s * 4 + 3] * inv);
        *(ushort4*)(row + (s * 256 + tid) * 4) = o;
    }
}

// ---------------------------------------------------------------------------
// GEMM-C: out[n,md] = attn @ memory, f32 out.
// BM=64, BN=64, K-step 64 -> grid (16,32) = 512 blocks (2/CU), LDS 16 KB
// ---------------------------------------------------------------------------
template<int BM, int BN>
__global__ __launch_bounds__(256, 4)
void k_gemm_out(const u16* __restrict__ AT, const u16* __restrict__ MEMT,
                float* __restrict__ out)
{
    constexpr int MT = BM / 32, NT = BN / 32;
    __shared__ __align__(16) u16 smem[2 * (BM + BN) * 32];
    f32x4 acc[MT][NT];
    const int row0 = blockIdx.y * BM, col0 = blockIdx.x * BN;
    u16* sA0 = smem;
    u16* sB0 = sA0 + BM * 32;
    u16* sA1 = sB0 + BN * 32;
    u16* sB1 = sA1 + BM * 32;
    gemm_core2<BM, BN>(AT, MEMT, 8192, row0, col0, sA0, sB0, sA1, sB1, acc);

    const int tid = threadIdx.x, lane = tid & 63, wv = tid >> 6;
    const int wr = wv >> 1, wc = wv & 1, lr = lane & 15, kg = lane >> 4;
    int mm[NT];
#pragma unroll
    for (int j = 0; j < NT; j++) mm[j] = col0 + wc * (BN / 2) + j * 16 + lr;
#pragma unroll
    for (int i = 0; i < MT; i++)
#pragma unroll
        for (int r = 0; r < 4; r++) {
            int n = row0 + wr * (BM / 2) + i * 16 + kg * 4 + r;
            size_t ob = (size_t)n * 1024;
#pragma unroll
            for (int j = 0; j < NT; j++)
                out[ob + mm[j]] = acc[i][j][r];
        }
}

// sentinel: distinctive output if workspace is too small (absmax ~12345)
__global__ void k_fill(float* out, int n)
{
    int i = blockIdx.x * 256 + threadIdx.x;
    if (i < n) out[i] = 12345.f;
}

// ---------------------------------------------------------------------------
extern "C" void kernel_launch(void* const* d_in, const int* in_sizes, int n_in,
                              void* d_out, int out_size, void* d_ws, size_t ws_size,
                              hipStream_t stream)
{
    const float* x     = (const float*)d_in[0];
    const float* w     = (const float*)d_in[1];
    const float* delay = (const float*)d_in[2];
    const float* bb    = (const float*)d_in[3];
    const float* gW    = (const float*)d_in[4];
    const float* gb    = (const float*)d_in[5];
    const float* na    = (const float*)d_in[6];
    const float* cW1   = (const float*)d_in[7];
    const float* cb1   = (const float*)d_in[8];
    const float* cW2   = (const float*)d_in[9];
    const float* cb2   = (const float*)d_in[10];
    const float* mask  = (const float*)d_in[11];
    const float* actw  = (const float*)d_in[12];
    const float* rW    = (const float*)d_in[13];
    const float* rb    = (const float*)d_in[14];
    const float* mem   = (const float*)d_in[15];
    (void)in_sizes; (void)n_in;

    char* ws = (char*)d_ws;
    size_t off = 0;
    auto alloc = [&](size_t bytes) {
        size_t o = off; off += (bytes + 255) & ~(size_t)255; return o;
    };
    size_t o_wts   = alloc(9 * 4);
    size_t o_gate  = alloc(2048 * 4 * 4);
    size_t o_conn  = alloc(2048 * 4);
    size_t o_y     = alloc((size_t)2048 * 4096 * 2);   // later aliased as memT
    size_t o_wmT   = alloc((size_t)2048 * 4096 * 2);
    size_t o_blend = alloc((size_t)2048 * 2048 * 2);
    size_t o_rwT   = alloc((size_t)8192 * 2048 * 2);
    size_t o_log   = alloc((size_t)2048 * 8192 * 2);   // logits, then attn in-place

    if (off > ws_size) {   // loud, distinguishable failure mode
        k_fill<<<(out_size + 255) / 256, 256, 0, stream>>>((float*)d_out, out_size);
        return;
    }

    float* wts   = (float*)(ws + o_wts);
    float* gate  = (float*)(ws + o_gate);
    float* conn  = (float*)(ws + o_conn);
    u16* y       = (u16*)(ws + o_y);
    u16* wmT     = (u16*)(ws + o_wmT);
    u16* blend   = (u16*)(ws + o_blend);
    u16* rwT     = (u16*)(ws + o_rwT);
    u16* logits  = (u16*)(ws + o_log);
    u16* memT    = y;   // y dead after k_gemm_blend; same size (16 MB)

    k_small<<<1, 256, 0, stream>>>(na, cW1, cb1, cW2, cb2, actw, conn, wts);
    k_gate_y<<<512, 256, 0, stream>>>(x, gW, gb, gate, y);
    k_wmT<<<dim3(32, 32), 256, 0, stream>>>(w, delay, wmT);
    k_gemm_blend<128, 64><<<dim3(32, 16), 256, 0, stream>>>(y, wmT, gate, conn, wts, bb, mask, blend);
    k_transpose<<<dim3(128, 32), 256, 0, stream>>>(rW, rwT, 2048, 8192);
    k_gemm_logits<<<dim3(64, 16), 256, 0, stream>>>(blend, rwT, rb, logits);
    k_softmax<<<2048, 256, 0, stream>>>(logits);
    k_transpose<<<dim3(16, 128), 256, 0, stream>>>(mem, memT, 8192, 1024);
    k_gemm_out<64, 64><<<dim3(16, 32), 256, 0, stream>>>(logits, memT, (float*)d_out);
}

// Round 7
// 477.001 us; speedup vs baseline: 1.2306x; 1.0478x over previous
//
#include <hip/hip_runtime.h>

// ============================================================================
// PlasticityModelMoE — MI355X (gfx950). Inputs f32, output f32, bf16 MFMA.
// R7: double-buffered prefetch K-loop for ALL GEMMs (gemm_core_db):
//   per window: issue next window's global_load_lds into LDS set p^1,
//   compute (ds_read+MFMA) from set p, ONE __syncthreads (vmcnt drain now
//   overlapped by compute), swap. Per-set LDS layout identical to verified
//   m89/m91 fragment addressing. A:128x64,S=2 · B:128x128,S=1 · C:64x64,S=2.
// ============================================================================

typedef unsigned short u16;
typedef __attribute__((ext_vector_type(8))) short bf16x8;   // 8 bf16 = 4 VGPRs
typedef __attribute__((ext_vector_type(4))) float f32x4;

__device__ __forceinline__ float b2f(u16 h) {
    union { unsigned u; float f; } v; v.u = ((unsigned)h) << 16; return v.f;
}
__device__ __forceinline__ u16 f2b(float f) {
    union { float f; unsigned u; } v; v.f = f;
    unsigned u = v.u;
    return (u16)((u + 0x7fffu + ((u >> 16) & 1u)) >> 16);   // round-nearest-even
}

// async global->LDS, 16B per lane (wave-uniform base + lane*16 — m97 pattern).
__device__ __forceinline__ void async_copy16(void* lds, const void* g) {
    __builtin_amdgcn_global_load_lds(
        (__attribute__((address_space(1))) void*)(g),
        (__attribute__((address_space(3))) void*)(lds), 16, 0, 0);
}

// ---------------------------------------------------------------------------
// Double-buffered GEMM core: C[M,N] += A[M,K]*B[N,K]^T, bf16 in, f32 acc.
// S stages of BK=32 per barrier window (K-step 32*S). Two LDS sets; prefetch
// of window i+1 is issued BEFORE compute of window i; the single barrier's
// vmcnt(0) drain is overlapped by that compute.
// 256 thr, 4 waves 2x2, wave tile (BM/2)x(BN/2), mfma_f32_16x16x32_bf16.
// Layouts (m89/m91): A-frag A[m=lane&15][k=(lane>>4)*8+j]; B-frag same (n);
// C/D col(n)=lane&15, row(m)=(lane>>4)*4+reg.
// smem must hold 2 * (BM+BN) * 32 * S u16 elements.
// ---------------------------------------------------------------------------
template<int BM, int BN, int S>
__device__ __forceinline__ void gemm_core_db(const u16* __restrict__ A,
                                             const u16* __restrict__ B,
                                             int K, int row0, int col0,
                                             u16* smem,
                                             f32x4 (&acc)[BM / 32][BN / 32])
{
    constexpr int MT = BM / 32, NT = BN / 32;
    constexpr int STG = (BM + BN) * 32;     // u16 per stage
    constexpr int SET = STG * S;            // u16 per buffer set
    const int tid  = threadIdx.x;
    const int lane = tid & 63;
    const int wv   = tid >> 6;
    const int wr   = wv >> 1, wc = wv & 1;
    const int lr   = lane & 15, kg = lane >> 4;

#pragma unroll
    for (int i = 0; i < MT; i++)
#pragma unroll
        for (int j = 0; j < NT; j++) {
            f32x4 z = {0.f, 0.f, 0.f, 0.f};
            acc[i][j] = z;
        }

    auto stage_in = [&](u16* set, int k0) {
#pragma unroll
        for (int c = tid; c < BM * 4; c += 256) {
            const u16* gA = A + (size_t)(row0 + (c >> 2)) * K + k0 + (c & 3) * 8;
#pragma unroll
            for (int s = 0; s < S; s++)
                async_copy16(set + s * STG + c * 8, gA + s * 32);
        }
#pragma unroll
        for (int c = tid; c < BN * 4; c += 256) {
            const u16* gB = B + (size_t)(col0 + (c >> 2)) * K + k0 + (c & 3) * 8;
#pragma unroll
            for (int s = 0; s < S; s++)
                async_copy16(set + s * STG + BM * 32 + c * 8, gB + s * 32);
        }
    };

    stage_in(smem, 0);
    __syncthreads();           // drain prologue staging

    int p = 0;
    for (int k0 = 0; k0 < K; k0 += 32 * S) {
        if (k0 + 32 * S < K)
            stage_in(smem + (p ^ 1) * SET, k0 + 32 * S);   // prefetch next window
        u16* set = smem + p * SET;
#pragma unroll
        for (int s = 0; s < S; s++) {
            const u16* sA = set + s * STG;
            const u16* sB = sA + BM * 32;
            bf16x8 af[MT], bfr[NT];
#pragma unroll
            for (int i = 0; i < MT; i++)
                af[i] = *(const bf16x8*)(sA + ((wr * (BM / 2) + i * 16 + lr) * 32 + kg * 8));
#pragma unroll
            for (int j = 0; j < NT; j++)
                bfr[j] = *(const bf16x8*)(sB + ((wc * (BN / 2) + j * 16 + lr) * 32 + kg * 8));
#pragma unroll
            for (int i = 0; i < MT; i++)
#pragma unroll
                for (int j = 0; j < NT; j++)
                    acc[i][j] = __builtin_amdgcn_mfma_f32_16x16x32_bf16(
                                    af[i], bfr[j], acc[i][j], 0, 0, 0);
        }
        __syncthreads();       // one barrier/window; vmcnt drain overlapped above
        p ^= 1;
    }
}

// ---------------------------------------------------------------------------
// tiny: conn = sigmoid(relu(na@W1+b1)@W2+b2), wts = softmax(act_w). All f32.
// ---------------------------------------------------------------------------
__global__ __launch_bounds__(256)
void k_small(const float* __restrict__ na, const float* __restrict__ W1,
             const float* __restrict__ b1, const float* __restrict__ W2,
             const float* __restrict__ b2, const float* __restrict__ actw,
             float* __restrict__ conn, float* __restrict__ wts)
{
    __shared__ float red[256 * 32];
    __shared__ float hsh[32];
    const int tid = threadIdx.x;
    float h[32];
#pragma unroll
    for (int k = 0; k < 32; k++) h[k] = 0.f;
    for (int u = tid; u < 2048; u += 256) {
        float nav = na[u];
        const float* row = W1 + u * 32;
#pragma unroll
        for (int k = 0; k < 32; k++) h[k] += nav * row[k];
    }
#pragma unroll
    for (int k = 0; k < 32; k++) red[tid * 32 + k] = h[k];
    for (int s = 128; s > 0; s >>= 1) {
        __syncthreads();
        if (tid < s)
#pragma unroll
            for (int k = 0; k < 32; k++) red[tid * 32 + k] += red[(tid + s) * 32 + k];
    }
    __syncthreads();
    if (tid < 32) hsh[tid] = fmaxf(red[tid] + b1[tid], 0.f);
    if (tid == 0) {
        float e[9], m = -1e30f;
        for (int i = 0; i < 9; i++) { e[i] = actw[i]; m = fmaxf(m, e[i]); }
        float s = 0.f;
        for (int i = 0; i < 9; i++) { e[i] = expf(e[i] - m); s += e[i]; }
        for (int i = 0; i < 9; i++) wts[i] = e[i] / s;
    }
    __syncthreads();
    for (int u = tid; u < 2048; u += 256) {
        float a = 0.f;
#pragma unroll
        for (int k = 0; k < 32; k++) a += hsh[k] * W2[k * 2048 + u];
        conn[u] = 1.f / (1.f + expf(-(a + b2[u])));
    }
}

// ---------------------------------------------------------------------------
// gate softmax + y = x*gate (bf16 out). One wave per row n.
// ---------------------------------------------------------------------------
__global__ __launch_bounds__(256)
void k_gate_y(const float* __restrict__ x, const float* __restrict__ gW,
              const float* __restrict__ gb, float* __restrict__ gate,
              u16* __restrict__ y)
{
    const int tid = threadIdx.x, lane = tid & 63, wv = tid >> 6;
    const int n = blockIdx.x * 4 + wv;
    const float* xr = x + (size_t)n * 1024;
    float a0 = 0, a1 = 0, a2 = 0, a3 = 0;
    float xv[16];
#pragma unroll
    for (int s = 0; s < 16; s++) {
        int d = s * 64 + lane;
        float xd = xr[d]; xv[s] = xd;
        float4 g4 = *(const float4*)(gW + d * 4);
        a0 += xd * g4.x; a1 += xd * g4.y; a2 += xd * g4.z; a3 += xd * g4.w;
    }
#pragma unroll
    for (int off = 32; off > 0; off >>= 1) {
        a0 += __shfl_xor(a0, off); a1 += __shfl_xor(a1, off);
        a2 += __shfl_xor(a2, off); a3 += __shfl_xor(a3, off);
    }
    a0 += gb[0]; a1 += gb[1]; a2 += gb[2]; a3 += gb[3];
    float m = fmaxf(fmaxf(a0, a1), fmaxf(a2, a3));
    float e0 = expf(a0 - m), e1 = expf(a1 - m), e2 = expf(a2 - m), e3 = expf(a3 - m);
    float inv = 1.f / (e0 + e1 + e2 + e3);
    float g0 = e0 * inv, g1 = e1 * inv, g2 = e2 * inv, g3 = e3 * inv;
    if (lane == 0) *(float4*)(gate + n * 4) = make_float4(g0, g1, g2, g3);
#pragma unroll
    for (int s = 0; s < 16; s++) {
        int d = s * 64 + lane;
        ushort4 o;
        o.x = f2b(xv[s] * g0); o.y = f2b(xv[s] * g1);
        o.z = f2b(xv[s] * g2); o.w = f2b(xv[s] * g3);
        *(ushort4*)(y + (size_t)n * 4096 + d * 4) = o;
    }
}

// ---------------------------------------------------------------------------
// wmT[u, d*4+b] = w[d,u,b] * sigmoid(delay[d,u,b]); f32 in, bf16 out.
// ---------------------------------------------------------------------------
__global__ __launch_bounds__(256)
void k_wmT(const float* __restrict__ w, const float* __restrict__ delay,
           u16* __restrict__ wmT)
{
    __shared__ __align__(16) ushort4 tile[32][65];
    const int tid = threadIdx.x;
    const int tx = tid & 63, ty = tid >> 6;          // tx: u, ty: d-subset
    const int u0 = blockIdx.x * 64, d0 = blockIdx.y * 32;
#pragma unroll
    for (int i = 0; i < 8; i++) {
        int d = i * 4 + ty;
        size_t idx = ((size_t)(d0 + d) * 2048 + (u0 + tx)) * 4;
        float4 w4 = *(const float4*)(w + idx);
        float4 d4 = *(const float4*)(delay + idx);
        ushort4 o;
        o.x = f2b(w4.x / (1.f + expf(-d4.x)));
        o.y = f2b(w4.y / (1.f + expf(-d4.y)));
        o.z = f2b(w4.z / (1.f + expf(-d4.z)));
        o.w = f2b(w4.w / (1.f + expf(-d4.w)));
        tile[d][tx] = o;
    }
    __syncthreads();
    const int dx = tid & 31, uy = tid >> 5;
#pragma unroll
    for (int i = 0; i < 8; i++) {
        int u = i * 8 + uy;
        *(ushort4*)(wmT + (size_t)(u0 + u) * 4096 + (d0 + dx) * 4) = tile[dx][u];
    }
}

// ---------------------------------------------------------------------------
// transpose + cast: in[R,C] f32 -> out[C,R] bf16, 64x64 tiles
// ---------------------------------------------------------------------------
__global__ __launch_bounds__(256)
void k_transpose(const float* __restrict__ in, u16* __restrict__ out, int R, int C)
{
    __shared__ __align__(16) u16 t[64][68];
    const int tid = threadIdx.x, tx = tid & 15, ty = tid >> 4;
    const int c0 = blockIdx.x * 64, r0 = blockIdx.y * 64;
#pragma unroll
    for (int i = 0; i < 4; i++) {
        int r = r0 + ty + i * 16;
        float4 v = *(const float4*)(in + (size_t)r * C + c0 + tx * 4);
        t[tx * 4 + 0][ty + i * 16] = f2b(v.x); t[tx * 4 + 1][ty + i * 16] = f2b(v.y);
        t[tx * 4 + 2][ty + i * 16] = f2b(v.z); t[tx * 4 + 3][ty + i * 16] = f2b(v.w);
    }
    __syncthreads();
#pragma unroll
    for (int i = 0; i < 4; i++) {
        int c = ty + i * 16;
        ushort4 v;
        v.x = t[c][tx * 4 + 0]; v.y = t[c][tx * 4 + 1];
        v.z = t[c][tx * 4 + 2]; v.w = t[c][tx * 4 + 3];
        *(ushort4*)(out + (size_t)(c0 + c) * R + r0 + tx * 4) = v;
    }
}

// ---------------------------------------------------------------------------
// 8-way activation blend
// ---------------------------------------------------------------------------
__device__ __forceinline__ float act_blend(float a,
    float w0, float w1, float w2, float w3,
    float w4, float w5, float w6, float w7)
{
    float sig = 1.f / (1.f + expf(-a));
    float elu = (a > 0.f) ? a : (expf(a) - 1.f);
    float th  = tanhf(a);
    float rel = fmaxf(a, 0.f);
    float sil = a * sig;
    float gel = a * 0.5f * (1.f + erff(a * 0.70710678118654752f));
    float sel = (a > 0.f) ? 1.0507009873554805f * a
                          : 1.0507009873554805f * 1.6732632423543772f * (expf(a) - 1.f);
    float sp  = (a > 20.f) ? a : log1pf(expf(a));
    float mish = a * tanhf(sp);
    return w0 * sig + w1 * elu + w2 * th + w3 * rel + w4 * sil + w5 * gel
         + w6 * sel + w7 * mish;
}

// ---------------------------------------------------------------------------
// GEMM-A: blend[n,u] = blend8(relu((y@wmT^T + b·gate)[n,u]*conn[u]*mask[u]))
// BM=128, BN=64, S=2, dbuf -> LDS 48 KB, grid (32,16)=512 (2/CU)
// ---------------------------------------------------------------------------
template<int BM, int BN>
__global__ __launch_bounds__(256, 4)
void k_gemm_blend(const u16* __restrict__ Y, const u16* __restrict__ WMT,
                  const float* __restrict__ gate, const float* __restrict__ conn,
                  const float* __restrict__ wts,
                  const float* __restrict__ bbias, const float* __restrict__ mask,
                  u16* __restrict__ blend)
{
    constexpr int MT = BM / 32, NT = BN / 32;
    __shared__ __align__(16) u16 smem[2 * (BM + BN) * 32 * 2];
    f32x4 acc[MT][NT];
    const int row0 = blockIdx.y * BM, col0 = blockIdx.x * BN;
    gemm_core_db<BM, BN, 2>(Y, WMT, 4096, row0, col0, smem, acc);

    const int tid = threadIdx.x, lane = tid & 63, wv = tid >> 6;
    const int wr = wv >> 1, wc = wv & 1, lr = lane & 15, kg = lane >> 4;
    const float w0 = wts[0], w1 = wts[1], w2 = wts[2], w3 = wts[3];
    const float w4 = wts[4], w5 = wts[5], w6 = wts[6], w7 = wts[7];

    float cm[NT], bb0[NT], bb1[NT], bb2[NT], bb3[NT];
    int uu[NT];
#pragma unroll
    for (int j = 0; j < NT; j++) {
        int u = col0 + wc * (BN / 2) + j * 16 + lr;
        uu[j] = u;
        cm[j] = conn[u] * mask[u];
        float4 b4 = *(const float4*)(bbias + u * 4);
        bb0[j] = b4.x; bb1[j] = b4.y; bb2[j] = b4.z; bb3[j] = b4.w;
    }
#pragma unroll
    for (int i = 0; i < MT; i++) {
#pragma unroll
        for (int r = 0; r < 4; r++) {
            int n = row0 + wr * (BM / 2) + i * 16 + kg * 4 + r;
            float4 g = *(const float4*)(gate + n * 4);
            size_t ob = (size_t)n * 2048;
#pragma unroll
            for (int j = 0; j < NT; j++) {
                float z = acc[i][j][r] + g.x * bb0[j] + g.y * bb1[j]
                                       + g.z * bb2[j] + g.w * bb3[j];
                float a = fmaxf(z * cm[j], 0.f);
                blend[ob + uu[j]] = f2b(act_blend(a, w0, w1, w2, w3, w4, w5, w6, w7));
            }
        }
    }
}

// ---------------------------------------------------------------------------
// GEMM-B: logits[n,m] = blend@read_W + read_b (bf16 out; softmaxed in place)
// 128x128, S=1, dbuf -> LDS 32 KB, grid (64,16)=1024 (4/CU)
// ---------------------------------------------------------------------------
__global__ __launch_bounds__(256, 2)
void k_gemm_logits(const u16* __restrict__ BL, const u16* __restrict__ RWT,
                   const float* __restrict__ rbias, u16* __restrict__ out)
{
    __shared__ __align__(16) u16 smem[2 * (128 + 128) * 32];
    f32x4 acc[4][4];
    const int row0 = blockIdx.y * 128, col0 = blockIdx.x * 128;
    gemm_core_db<128, 128, 1>(BL, RWT, 2048, row0, col0, smem, acc);

    const int tid = threadIdx.x, lane = tid & 63, wv = tid >> 6;
    const int wr = wv >> 1, wc = wv & 1, lr = lane & 15, kg = lane >> 4;
    float rb[4]; int mm[4];
#pragma unroll
    for (int j = 0; j < 4; j++) {
        mm[j] = col0 + wc * 64 + j * 16 + lr;
        rb[j] = rbias[mm[j]];
    }
#pragma unroll
    for (int i = 0; i < 4; i++)
#pragma unroll
        for (int r = 0; r < 4; r++) {
            int n = row0 + wr * 64 + i * 16 + kg * 4 + r;
            size_t ob = (size_t)n * 8192;
#pragma unroll
            for (int j = 0; j < 4; j++)
                out[ob + mm[j]] = f2b(acc[i][j][r] + rb[j]);
        }
}

// ---------------------------------------------------------------------------
// in-place row softmax over 8192 bf16 (one block per row, values in registers)
// ---------------------------------------------------------------------------
__global__ __launch_bounds__(256)
void k_softmax(u16* __restrict__ buf)
{
    __shared__ float red[8];
    const int tid = threadIdx.x, lane = tid & 63, wv = tid >> 6;
    u16* row = buf + (size_t)blockIdx.x * 8192;
    float v[32];
    float mx = -1e30f;
#pragma unroll
    for (int s = 0; s < 8; s++) {
        ushort4 u4 = *(const ushort4*)(row + (s * 256 + tid) * 4);
        float a = b2f(u4.x), b = b2f(u4.y), c = b2f(u4.z), d = b2f(u4.w);
        v[s * 4 + 0] = a; v[s * 4 + 1] = b; v[s * 4 + 2] = c; v[s * 4 + 3] = d;
        mx = fmaxf(mx, fmaxf(fmaxf(a, b), fmaxf(c, d)));
    }
#pragma unroll
    for (int off = 32; off > 0; off >>= 1) mx = fmaxf(mx, __shfl_xor(mx, off));
    if (lane == 0) red[wv] = mx;
    __syncthreads();
    mx = fmaxf(fmaxf(red[0], red[1]), fmaxf(red[2], red[3]));
    float sum = 0.f;
#pragma unroll
    for (int k = 0; k < 32; k++) { v[k] = expf(v[k] - mx); sum += v[k]; }
#pragma unroll
    for (int off = 32; off > 0; off >>= 1) sum += __shfl_xor(sum, off);
    if (lane == 0) red[4 + wv] = sum;
    __syncthreads();
    float inv = 1.f / (red[4] + red[5] + red[6] + red[7]);
#pragma unroll
    for (int s = 0; s < 8; s++) {
        ushort4 o;
        o.x = f2b(v[s * 4 + 0] * inv); o.y = f2b(v[s * 4 + 1] * inv);
        o.z = f2b(v[s * 4 + 2] * inv); o.w = f2b(v[s * 4 + 3] * inv);
        *(ushort4*)(row + (s * 256 + tid) * 4) = o;
    }
}

// ---------------------------------------------------------------------------
// GEMM-C: out[n,md] = attn @ memory, f32 out.
// BM=64, BN=64, S=2, dbuf -> LDS 32 KB, grid (16,32)=512 (2/CU)
// ---------------------------------------------------------------------------
template<int BM, int BN>
__global__ __launch_bounds__(256, 4)
void k_gemm_out(const u16* __restrict__ AT, const u16* __restrict__ MEMT,
                float* __restrict__ out)
{
    constexpr int MT = BM / 32, NT = BN / 32;
    __shared__ __align__(16) u16 smem[2 * (BM + BN) * 32 * 2];
    f32x4 acc[MT][NT];
    const int row0 = blockIdx.y * BM, col0 = blockIdx.x * BN;
    gemm_core_db<BM, BN, 2>(AT, MEMT, 8192, row0, col0, smem, acc);

    const int tid = threadIdx.x, lane = tid & 63, wv = tid >> 6;
    const int wr = wv >> 1, wc = wv & 1, lr = lane & 15, kg = lane >> 4;
    int mm[NT];
#pragma unroll
    for (int j = 0; j < NT; j++) mm[j] = col0 + wc * (BN / 2) + j * 16 + lr;
#pragma unroll
    for (int i = 0; i < MT; i++)
#pragma unroll
        for (int r = 0; r < 4; r++) {
            int n = row0 + wr * (BM / 2) + i * 16 + kg * 4 + r;
            size_t ob = (size_t)n * 1024;
#pragma unroll
            for (int j = 0; j < NT; j++)
                out[ob + mm[j]] = acc[i][j][r];
        }
}

// sentinel: distinctive output if workspace is too small (absmax ~12345)
__global__ void k_fill(float* out, int n)
{
    int i = blockIdx.x * 256 + threadIdx.x;
    if (i < n) out[i] = 12345.f;
}

// ---------------------------------------------------------------------------
extern "C" void kernel_launch(void* const* d_in, const int* in_sizes, int n_in,
                              void* d_out, int out_size, void* d_ws, size_t ws_size,
                              hipStream_t stream)
{
    const float* x     = (const float*)d_in[0];
    const float* w     = (const float*)d_in[1];
    const float* delay = (const float*)d_in[2];
    const float* bb    = (const float*)d_in[3];
    const float* gW    = (const float*)d_in[4];
    const float* gb    = (const float*)d_in[5];
    const float* na    = (const float*)d_in[6];
    const float* cW1   = (const float*)d_in[7];
    const float* cb1   = (const float*)d_in[8];
    const float* cW2   = (const float*)d_in[9];
    const float* cb2   = (const float*)d_in[10];
    const float* mask  = (const float*)d_in[11];
    const float* actw  = (const float*)d_in[12];
    const float* rW    = (const float*)d_in[13];
    const float* rb    = (const float*)d_in[14];
    const float* mem   = (const float*)d_in[15];
    (void)in_sizes; (void)n_in;

    char* ws = (char*)d_ws;
    size_t off = 0;
    auto alloc = [&](size_t bytes) {
        size_t o = off; off += (bytes + 255) & ~(size_t)255; return o;
    };
    size_t o_wts   = alloc(9 * 4);
    size_t o_gate  = alloc(2048 * 4 * 4);
    size_t o_conn  = alloc(2048 * 4);
    size_t o_y     = alloc((size_t)2048 * 4096 * 2);   // later aliased as memT
    size_t o_wmT   = alloc((size_t)2048 * 4096 * 2);
    size_t o_blend = alloc((size_t)2048 * 2048 * 2);
    size_t o_rwT   = alloc((size_t)8192 * 2048 * 2);
    size_t o_log   = alloc((size_t)2048 * 8192 * 2);   // logits, then attn in-place

    if (off > ws_size) {   // loud, distinguishable failure mode
        k_fill<<<(out_size + 255) / 256, 256, 0, stream>>>((float*)d_out, out_size);
        return;
    }

    float* wts   = (float*)(ws + o_wts);
    float* gate  = (float*)(ws + o_gate);
    float* conn  = (float*)(ws + o_conn);
    u16* y       = (u16*)(ws + o_y);
    u16* wmT     = (u16*)(ws + o_wmT);
    u16* blend   = (u16*)(ws + o_blend);
    u16* rwT     = (u16*)(ws + o_rwT);
    u16* logits  = (u16*)(ws + o_log);
    u16* memT    = y;   // y dead after k_gemm_blend; same size (16 MB)

    k_small<<<1, 256, 0, stream>>>(na, cW1, cb1, cW2, cb2, actw, conn, wts);
    k_gate_y<<<512, 256, 0, stream>>>(x, gW, gb, gate, y);
    k_wmT<<<dim3(32, 32), 256, 0, stream>>>(w, delay, wmT);
    k_gemm_blend<128, 64><<<dim3(32, 16), 256, 0, stream>>>(y, wmT, gate, conn, wts, bb, mask, blend);
    k_transpose<<<dim3(128, 32), 256, 0, stream>>>(rW, rwT, 2048, 8192);
    k_gemm_logits<<<dim3(64, 16), 256, 0, stream>>>(blend, rwT, rb, logits);
    k_softmax<<<2048, 256, 0, stream>>>(logits);
    k_transpose<<<dim3(16, 128), 256, 0, stream>>>(mem, memT, 8192, 1024);
    k_gemm_out<64, 64><<<dim3(16, 32), 256, 0, stream>>>(logits, memT, (float*)d_out);
}